// Round 1
// baseline (362.016 us; speedup 1.0000x reference)
//
#include <hip/hip_runtime.h>
#include <cmath>

#define Bdim 8
#define Cdim 768
#define Kdim 256
#define Ndim 4096
#define NT 64      // tokens per block in kernel 1
#define KC 16      // C-chunk staged in LDS
#define CB 16      // c-rows per block in kernel 2

// Kernel 1: per (b, n-tile of 64): cos over all K=256 centroids (fp32 GEMM),
// per-k sigmoid, first-win argmax, scatter sim_masked + counts + (w, k*) arrays.
__global__ __launch_bounds__(256) void sim_argmax_kernel(
    const float* __restrict__ x,        // (B,C,N)
    const float* __restrict__ cents,    // (B,C,K)
    const float* __restrict__ alpha_p,
    const float* __restrict__ beta_p,
    float* __restrict__ simOut,         // (B,K,N), pre-zeroed
    float* __restrict__ wArr,           // (B,N)
    int*   __restrict__ kArr,           // (B,N)
    int*   __restrict__ cnt)            // (B,K), pre-zeroed
{
    __shared__ float sc[KC][Kdim];      // 16 KB centroid chunk
    __shared__ float sx[KC][NT];        // 4 KB  x chunk
    __shared__ float invc[Kdim];
    __shared__ float invx[NT];
    __shared__ float px[4][NT];
    __shared__ float bval[32][NT];      // 8 KB per-kgroup best sim
    __shared__ int   bidx[32][NT];      // 8 KB per-kgroup best k

    const int tid = threadIdx.x;
    const int b   = blockIdx.x / (Ndim / NT);
    const int n0  = (blockIdx.x % (Ndim / NT)) * NT;
    const float* xb = x     + (size_t)b * Cdim * Ndim;
    const float* cb = cents + (size_t)b * Cdim * Kdim;

    const int kb = (tid >> 3) * 8;      // 8 consecutive k per thread
    const int nb = (tid & 7) * 8;       // 8 consecutive n per thread

    float acc[8][8];
    #pragma unroll
    for (int i = 0; i < 8; ++i)
        #pragma unroll
        for (int j = 0; j < 8; ++j) acc[i][j] = 0.f;

    float cn2  = 0.f;   // thread t accumulates ||centroid k=t||^2
    float xn2p = 0.f;   // partial ||x_n||^2: (group tid>>6, n=tid&63)

    for (int c0 = 0; c0 < Cdim; c0 += KC) {
        #pragma unroll
        for (int i = 0; i < 4; ++i) {   // 1024 float4 of centroid chunk
            int idx = tid + i * 256;
            int r = idx >> 6, c4 = idx & 63;
            ((float4*)sc)[idx] = ((const float4*)(cb + (size_t)(c0 + r) * Kdim))[c4];
        }
        {
            int r = tid >> 4, c4 = tid & 15;  // 256 float4 of x chunk
            ((float4*)sx)[tid] = *(const float4*)(xb + (size_t)(c0 + r) * Ndim + n0 + c4 * 4);
        }
        __syncthreads();

        // norm accumulation from staged tiles (cheap, no divergence)
        #pragma unroll
        for (int r = 0; r < KC; ++r) { float v = sc[r][tid]; cn2 = fmaf(v, v, cn2); }
        #pragma unroll
        for (int r = 0; r < 4; ++r) { float v = sx[(tid >> 6) * 4 + r][tid & 63]; xn2p = fmaf(v, v, xn2p); }

        // main 8x8 FMA tile
        #pragma unroll
        for (int r = 0; r < KC; ++r) {
            float a0[8], b0[8];
            *(float4*)(a0)     = *(const float4*)&sc[r][kb];
            *(float4*)(a0 + 4) = *(const float4*)&sc[r][kb + 4];
            *(float4*)(b0)     = *(const float4*)&sx[r][nb];
            *(float4*)(b0 + 4) = *(const float4*)&sx[r][nb + 4];
            #pragma unroll
            for (int i = 0; i < 8; ++i)
                #pragma unroll
                for (int j = 0; j < 8; ++j)
                    acc[i][j] = fmaf(a0[i], b0[j], acc[i][j]);
        }
        __syncthreads();
    }

    invc[tid] = 1.f / fmaxf(sqrtf(cn2), 1e-12f);
    px[tid >> 6][tid & 63] = xn2p;
    __syncthreads();
    if (tid < NT) {
        float s = px[0][tid] + px[1][tid] + px[2][tid] + px[3][tid];
        invx[tid] = 1.f / fmaxf(sqrtf(s), 1e-12f);
    }
    __syncthreads();

    const float alpha = alpha_p[0];
    const float beta  = beta_p[0];

    // per-thread argmax over its 8 k (ascending, strict > = first-win),
    // replicating reference: sigmoid applied per-k in fp32 before compare
    #pragma unroll
    for (int j = 0; j < 8; ++j) {
        int n = nb + j;
        float ix = invx[n];
        float best = -1.f; int bkk = 0;
        #pragma unroll
        for (int i = 0; i < 8; ++i) {
            float cosv = acc[i][j] * invc[kb + i] * ix;
            float s = 1.f / (1.f + expf(-(beta + alpha * cosv)));
            if (s > best) { best = s; bkk = kb + i; }
        }
        bval[tid >> 3][n] = best;
        bidx[tid >> 3][n] = bkk;
    }
    __syncthreads();
    if (tid < NT) {
        int n = tid;
        float best = -1.f; int bkk = 0;
        for (int g = 0; g < 32; ++g) {   // ascending k-groups = first-win preserved
            float v = bval[g][n];
            if (v > best) { best = v; bkk = bidx[g][n]; }
        }
        int gn = b * Ndim + n0 + n;
        wArr[gn] = best;
        kArr[gn] = bkk;
        simOut[((size_t)(b * Kdim + bkk)) * Ndim + n0 + n] = best;
        atomicAdd(&cnt[b * Kdim + bkk], 1);
    }
}

// Kernel 2: per (b, 16 c-rows): stream all N tokens coalesced, LDS-atomic
// scatter into acc[c][k], then fused (agg + ct)/(cnt+1) epilogue with
// coalesced (B,K,C) writes.
__global__ __launch_bounds__(256) void agg_kernel(
    const float* __restrict__ x,        // (B,C,N)
    const float* __restrict__ cents,    // (B,C,K)
    const float* __restrict__ wArr,
    const int*   __restrict__ kArr,
    const int*   __restrict__ cnt,
    float* __restrict__ hyp)            // (B,K,C)
{
    __shared__ float accs[CB][Kdim];    // 16 KB
    __shared__ float wS[Ndim];          // 16 KB
    __shared__ int   kS[Ndim];          // 16 KB
    const int tid = threadIdx.x;
    const int b  = blockIdx.x / (Cdim / CB);
    const int c0 = (blockIdx.x % (Cdim / CB)) * CB;

    for (int i = tid; i < CB * Kdim; i += 256) ((float*)accs)[i] = 0.f;
    for (int i = tid; i < Ndim; i += 256) { wS[i] = wArr[b * Ndim + i]; kS[i] = kArr[b * Ndim + i]; }
    __syncthreads();

    const float* xb = x + (size_t)b * Cdim * Ndim;
    for (int r = 0; r < CB; ++r) {
        const float* row = xb + (size_t)(c0 + r) * Ndim;
        for (int i = tid; i < Ndim; i += 256) {
            atomicAdd(&accs[r][kS[i]], wS[i] * row[i]);   // ds_add_f32, bank=k&31
        }
    }
    __syncthreads();

    const int cl = tid & 15;
    const int kq = tid >> 4;
    for (int k = kq; k < Kdim; k += 16) {
        float num = accs[cl][k] + cents[(size_t)b * Cdim * Kdim + (size_t)(c0 + cl) * Kdim + k];
        float v = num / (float)(cnt[b * Kdim + k] + 1);
        hyp[((size_t)(b * Kdim + k)) * Cdim + c0 + cl] = v;
    }
}

extern "C" void kernel_launch(void* const* d_in, const int* in_sizes, int n_in,
                              void* d_out, int out_size, void* d_ws, size_t ws_size,
                              hipStream_t stream)
{
    const float* x     = (const float*)d_in[0];
    const float* cents = (const float*)d_in[1];
    const float* alpha = (const float*)d_in[2];
    const float* beta  = (const float*)d_in[3];

    float* hyp    = (float*)d_out;                                    // (B,K,C)
    float* simOut = (float*)d_out + (size_t)Bdim * Kdim * Cdim;       // (B,K,N)

    float* wArr = (float*)d_ws;
    int*   kArr = (int*)((char*)d_ws + (size_t)Bdim * Ndim * sizeof(float));
    int*   cnt  = (int*)((char*)d_ws + 2 * (size_t)Bdim * Ndim * sizeof(float));

    hipMemsetAsync(cnt, 0, Bdim * Kdim * sizeof(int), stream);
    hipMemsetAsync(simOut, 0, (size_t)Bdim * Kdim * Ndim * sizeof(float), stream);

    sim_argmax_kernel<<<dim3(Bdim * (Ndim / NT)), dim3(256), 0, stream>>>(
        x, cents, alpha, beta, simOut, wArr, kArr, cnt);
    agg_kernel<<<dim3(Bdim * (Cdim / CB)), dim3(256), 0, stream>>>(
        x, cents, wArr, kArr, cnt, hyp);
}